// Round 13
// baseline (816.814 us; speedup 1.0000x reference)
//
#include <hip/hip_runtime.h>

typedef _Float16 f16;
typedef _Float16 f16x8 __attribute__((ext_vector_type(8)));
typedef _Float16 f16x4 __attribute__((ext_vector_type(4)));
typedef _Float16 f16x2 __attribute__((ext_vector_type(2)));
typedef float f32x4 __attribute__((ext_vector_type(4)));

#define MFMA16(a, b, c) __builtin_amdgcn_mfma_f32_16x16x32_f16(a, b, c, 0, 0, 0)

// ws layout (f16 elems): [0,110592) Wqkv frags | [110592,147456) Wout frags
#define WS_NEED 294912

// LDS arena granule (16 B) offsets — total 10000 granules = 160000 B
#define G_Q    0      // q  [64 tok][25g]
#define G_K    1600   // k  [64 tok][25g]
#define G_VT   3200   // v^T [192 ch][9g]
#define G_O    4928   // attn out [64 tok][25g]
#define G_P    6528   // P: 6 regions x 576g (aliases x-input staging)
#define G_XIN  6528   // x window [64 tok][25g] (dead after phase 1)
#define G_ADDR 9984   // int[64] scatter LUT

__device__ __forceinline__ float fast_exp2(float x) {
#if __has_builtin(__builtin_amdgcn_exp2f)
  return __builtin_amdgcn_exp2f(x);
#else
  float r;
  asm("v_exp_f32 %0, %1" : "=v"(r) : "v"(x));
  return r;
#endif
}

__device__ __forceinline__ f16x2 pkcvt(float a, float b) {
  auto r = __builtin_amdgcn_cvt_pkrtz(a, b);
  union { decltype(r) i; f16x2 o; } u;
  u.i = r;
  return u.o;
}

__device__ __forceinline__ f16x4 pk4(float a, float b, float c, float d) {
  union { f16x2 h2[2]; f16x4 h4; } u;
  u.h2[0] = pkcvt(a, b);
  u.h2[1] = pkcvt(c, d);
  return u.h4;
}

__device__ __forceinline__ f16x8 pk8(float4 a, float4 b) {
  union { f16x2 h2[4]; f16x8 h8; } u;
  u.h2[0] = pkcvt(a.x, a.y);
  u.h2[1] = pkcvt(a.z, a.w);
  u.h2[2] = pkcvt(b.x, b.y);
  u.h2[3] = pkcvt(b.z, b.w);
  return u.h8;
}

__device__ __forceinline__ f16x8 cvt8z(const float* p) {
  const float4* s = (const float4*)p;
  return pk8(s[0], s[1]);
}

__device__ __forceinline__ f16x8 cvt8(const float* p) {
  const float4* s = (const float4*)p;
  float4 u0 = s[0], u1 = s[1];
  f16x8 v;
  v[0] = (f16)u0.x; v[1] = (f16)u0.y; v[2] = (f16)u0.z; v[3] = (f16)u0.w;
  v[4] = (f16)u1.x; v[5] = (f16)u1.y; v[6] = (f16)u1.z; v[7] = (f16)u1.w;
  return v;
}

// ---- prep: W frags (f16, RTE) ----
__global__ void wmsa_prep(const float* __restrict__ Wqkv,
                          const float* __restrict__ Wout,
                          f16* __restrict__ ws) {
  int gid = blockIdx.x * 256 + threadIdx.x;
  if (gid < 13824) {
    int fb = gid >> 6, l = gid & 63;
    int kc = fb / 36, nt = fb - kc * 36;
    int n = nt * 16 + (l & 15), k = kc * 32 + (l >> 4) * 8;
    *(f16x8*)(ws + (size_t)gid * 8) = cvt8(Wqkv + (size_t)n * 192 + k);
  } else if (gid < 18432) {
    int g2 = gid - 13824;
    int fb = g2 >> 6, l = g2 & 63;
    int kc = fb / 12, nt = fb - kc * 12;
    int n = nt * 16 + (l & 15), k = kc * 32 + (l >> 4) * 8;
    *(f16x8*)(ws + 110592 + (size_t)g2 * 8) = cvt8(Wout + (size_t)n * 192 + k);
  }
}

// NH heads, interleaved chains, no-max softmax, REGISTER bias (no loads).
template <int NH>
__device__ __forceinline__ void attn_fast(
    f16* smem, const f32x4 (&bb)[2][4], int h0,
    int p, int lg, int l15, unsigned mbits, bool edge)
{
  const f32x4 zero4 = {0.f, 0.f, 0.f, 0.f};
  f16x8 aq[NH];
#pragma unroll
  for (int e = 0; e < NH; ++e)
    aq[e] = *(const f16x8*)&smem[(G_Q + p * 25 + (h0 + e) * 4 + lg) * 8];
  f32x4 sc[NH][4];
  __builtin_amdgcn_s_setprio(1);
#pragma unroll
  for (int e = 0; e < NH; ++e)
#pragma unroll
    for (int jq = 0; jq < 4; ++jq) {
      f16x8 bk = *(const f16x8*)&smem[(G_K + (16 * jq + l15) * 25 + (h0 + e) * 4 + lg) * 8];
      sc[e][jq] = MFMA16(bk, aq[e], zero4);
    }
  __builtin_amdgcn_s_setprio(0);

  float sv[NH][16];
#pragma unroll
  for (int e = 0; e < NH; ++e) {
    if (!edge) {
#pragma unroll
      for (int jq = 0; jq < 4; ++jq)
#pragma unroll
        for (int r = 0; r < 4; ++r)
          sv[e][jq * 4 + r] = fast_exp2(sc[e][jq][r] + bb[e][jq][r]);
    } else {
#pragma unroll
      for (int jq = 0; jq < 4; ++jq)
#pragma unroll
        for (int r = 0; r < 4; ++r) {
          int idx = jq * 4 + r;
          float s = (mbits >> idx & 1u) ? -30000.0f : sc[e][jq][r] + bb[e][jq][r];
          sv[e][idx] = fast_exp2(s);
        }
    }
  }
#pragma unroll
  for (int e = 0; e < NH; ++e)
#pragma unroll
    for (int jq = 0; jq < 4; ++jq) {
      f16x4 v = pk4(sv[e][jq * 4], sv[e][jq * 4 + 1], sv[e][jq * 4 + 2], sv[e][jq * 4 + 3]);
      *(f16x4*)&smem[(G_P + (h0 + e) * 576 + p * 9 + 2 * jq + (lg >> 1)) * 8 + (lg & 1) * 4] = v;
    }
  float inv[NH];
#pragma unroll
  for (int e = 0; e < NH; ++e) {
    float s0 = (sv[e][0] + sv[e][1]) + (sv[e][2] + sv[e][3]);
    float s1 = (sv[e][4] + sv[e][5]) + (sv[e][6] + sv[e][7]);
    float s2 = (sv[e][8] + sv[e][9]) + (sv[e][10] + sv[e][11]);
    float s3 = (sv[e][12] + sv[e][13]) + (sv[e][14] + sv[e][15]);
    float sum = (s0 + s1) + (s2 + s3);
    sum += __shfl_xor(sum, 16);
    sum += __shfl_xor(sum, 32);
    inv[e] = __builtin_amdgcn_rcpf(sum);
  }
  f32x4 o[NH][2];
#pragma unroll
  for (int e = 0; e < NH; ++e) { o[e][0] = zero4; o[e][1] = zero4; }
  __builtin_amdgcn_s_setprio(1);
#pragma unroll
  for (int e = 0; e < NH; ++e)
#pragma unroll
    for (int kq = 0; kq < 2; ++kq) {
      f16x8 ap = *(const f16x8*)&smem[(G_P + (h0 + e) * 576 + p * 9 + kq * 4 + lg) * 8];
#pragma unroll
      for (int jn = 0; jn < 2; ++jn) {
        int ch = (h0 + e) * 32 + jn * 16 + l15;
        f16x8 bv = *(const f16x8*)&smem[(G_VT + ch * 9 + kq * 4 + lg) * 8];
        o[e][jn] = MFMA16(bv, ap, o[e][jn]);
      }
    }
  __builtin_amdgcn_s_setprio(0);
#pragma unroll
  for (int e = 0; e < NH; ++e)
#pragma unroll
    for (int jn = 0; jn < 2; ++jn) {
      int ch0 = (h0 + e) * 32 + jn * 16 + lg * 4;
      f16x4 v = pk4(o[e][jn][0] * inv[e], o[e][jn][1] * inv[e],
                    o[e][jn][2] * inv[e], o[e][jn][3] * inv[e]);
      *(f16x4*)&smem[(G_O + p * 25 + (ch0 >> 3)) * 8 + (ch0 & 7)] = v;
    }
}

// Persistent: 256 blocks x 1024 threads; block b handles windows b*16 .. b*16+15.
// wi = b>>2 (constant), wj = (b&3)*16 + it.
__global__ __launch_bounds__(1024, 1) void wmsa_pers(
    const float* __restrict__ x,
    const float* __restrict__ bqkv,
    const float* __restrict__ relpos,
    const float* __restrict__ bout,
    const f16* __restrict__ ws,
    float* __restrict__ out)
{
  __shared__ __align__(16) f16 smem[10000 * 8];
  int* s_addr = (int*)&smem[G_ADDR * 8];

  const int tid = threadIdx.x;
  const int blk = blockIdx.x;
  const int wi = blk >> 2;
  const int wj0 = (blk & 3) * 16;
  const int wv = tid >> 6;
  const int l = tid & 63;
  const int l15 = l & 15, lg = l >> 4;
  const f32x4 zero4 = {0.f, 0.f, 0.f, 0.f};
  const float QMULT = 0.17677669529663687f * 1.4426950408889634f;

  // ---- resident weight fragments (kernel lifetime) ----
  f16x8 wA[12], wB[6];
  if (wv < 12) {
#pragma unroll
    for (int kc = 0; kc < 6; ++kc) {
      wA[kc * 2]     = *(const f16x8*)(ws + (size_t)(kc * 36 + 2 * wv) * 512 + l * 8);
      wA[kc * 2 + 1] = *(const f16x8*)(ws + (size_t)(kc * 36 + 2 * wv + 1) * 512 + l * 8);
      wB[kc]         = *(const f16x8*)(ws + 110592 + (size_t)(kc * 12 + wv) * 512 + l * 8);
    }
  } else {
    const int cv0 = (wv - 12) * 3;
#pragma unroll
    for (int kc = 0; kc < 4; ++kc)
#pragma unroll
      for (int ci = 0; ci < 3; ++ci)
        wA[kc * 3 + ci] = *(const f16x8*)(ws + (size_t)(kc * 36 + 24 + cv0 + ci) * 512 + l * 8);
#pragma unroll
    for (int kc = 4; kc < 6; ++kc)
#pragma unroll
      for (int ci = 0; ci < 3; ++ci)
        wB[(kc - 4) * 3 + ci] = *(const f16x8*)(ws + (size_t)(kc * 36 + 24 + cv0 + ci) * 512 + l * 8);
  }

  // ---- resident softmax bias (log2 domain) for this wave's heads ----
  const int pt = wv & 3, hi = wv >> 2;
  const int h0 = (hi < 2) ? hi * 2 : hi + 2;
  const int p = 16 * pt + l15;
  const int pi = p / 7, pj = p - pi * 7;
  f32x4 bb[2][4];
#pragma unroll
  for (int e = 0; e < 2; ++e) {
    int h = h0 + ((hi < 2) ? e : 0);
#pragma unroll
    for (int jq = 0; jq < 4; ++jq)
#pragma unroll
      for (int r = 0; r < 4; ++r) {
        int q = 16 * jq + lg * 4 + r;
        float v;
        if (q >= 49) v = -30000.0f;
        else if (p >= 49) v = 0.0f;
        else {
          int qi = q / 7, qj = q - qi * 7;
          int di = pi - qi, dj = pj - qj;
          float g = __expf((float)(di * di + dj * dj) * (-9.0f / 98.0f));
          v = (relpos[h * 169 + (di + 6) * 13 + (dj + 6)] + g) * 1.4426950408889634f;
        }
        bb[e][jq][r] = v;
      }
  }

  // ---- loop-invariant biases ----
  float4 bq4[2];   // qk waves: per ci
  float bv3[3];    // v waves
  float boutr = 0.0f;
  if (wv < 12) {
    bq4[0] = *(const float4*)(bqkv + (2 * wv) * 16 + lg * 4);
    bq4[1] = *(const float4*)(bqkv + (2 * wv + 1) * 16 + lg * 4);
    boutr = bout[wv * 16 + l15];
  } else {
    const int cv0 = (wv - 12) * 3;
    bv3[0] = bqkv[384 + (cv0 + 0) * 16 + l15];
    bv3[1] = bqkv[384 + (cv0 + 1) * 16 + l15];
    bv3[2] = bqkv[384 + (cv0 + 2) * 16 + l15];
  }

  // ---- prefetch thread mapping (loop-invariant) ----
  const int t0 = tid / 24, g0 = tid - t0 * 24;            // gid0 = tid
  const int t1 = (tid + 1024) / 24, g1 = (tid + 1024) - t1 * 24;  // tid<512

  // ---- prologue: stage x for window it=0 ----
  for (int gid = tid; gid < 1536; gid += 1024) {
    int t = gid / 24, g = gid - t * 24;
    f16x8 v;
    if (t < 49) {
      int hh = wi * 7 + t / 7 + 3; if (hh >= 448) hh -= 448;
      int ww = wj0 * 7 + t % 7 + 3; if (ww >= 448) ww -= 448;
      v = cvt8z(x + (size_t)(hh * 448 + ww) * 192 + g * 8);
    } else {
#pragma unroll
      for (int e2 = 0; e2 < 8; ++e2) v[e2] = (f16)0.0f;
    }
    *(f16x8*)&smem[(G_XIN + t * 25 + g) * 8] = v;
  }
  __syncthreads();

  for (int it = 0; it < 16; ++it) {
    const int wj = wj0 + it;
    // scatter LUT for this window (read 2 barriers later in phase 3)
    if (tid < 64) {
      int val = 0;
      if (tid < 49) {
        int i2 = tid / 7, j2 = tid - i2 * 7;
        int y = (wi & 15) * 7 + i2 + 3;  if (y >= 112) y -= 112;
        int xc = wj * 7 + j2 + 3;        if (xc >= 448) xc -= 448;
        val = (y * 448 + xc) * 768;
      }
      s_addr[tid] = val;
    }
    const bool edge = (wi == 63) || (wj == 63);
    unsigned mbits = 0;
    if (edge) {
#pragma unroll
      for (int jq = 0; jq < 4; ++jq)
#pragma unroll
        for (int r = 0; r < 4; ++r) {
          int q = 16 * jq + lg * 4 + r;
          int qi = q / 7, qj = q - qi * 7;
          bool bad = (q >= 49) || (p >= 49) ||
                     ((wi == 63) && ((pi < 4) != (qi < 4))) ||
                     ((wj == 63) && ((pj < 4) != (qj < 4)));
          if (bad) mbits |= (1u << (jq * 4 + r));
        }
    }

    // ---------------- Phase 1: QKV from resident frags ----------------------
    if (wv < 12) {
      f32x4 aqk[2][4];
#pragma unroll
      for (int ci = 0; ci < 2; ++ci)
#pragma unroll
        for (int t = 0; t < 4; ++t) aqk[ci][t] = zero4;
#pragma unroll
      for (int kc = 0; kc < 6; ++kc) {
        f16x8 xf[4];
#pragma unroll
        for (int t = 0; t < 4; ++t)
          xf[t] = *(const f16x8*)&smem[(G_XIN + (t * 16 + l15) * 25 + kc * 4 + lg) * 8];
#pragma unroll
        for (int t = 0; t < 4; ++t) aqk[0][t] = MFMA16(wA[kc * 2], xf[t], aqk[0][t]);
#pragma unroll
        for (int t = 0; t < 4; ++t) aqk[1][t] = MFMA16(wA[kc * 2 + 1], xf[t], aqk[1][t]);
      }
#pragma unroll
      for (int ci = 0; ci < 2; ++ci) {
        int c0 = (2 * wv + ci) * 16 + lg * 4;
        int part = (c0 >= 192) ? 1 : 0;
        int ch = c0 - part * 192;
        float mult = part ? 1.0f : QMULT;
        float bx = bq4[ci].x * mult, by = bq4[ci].y * mult;
        float bz = bq4[ci].z * mult, bw = bq4[ci].w * mult;
        int gbase = (part ? G_K : G_Q) + (ch >> 3);
        int sub = ch & 7;
#pragma unroll
        for (int t = 0; t < 4; ++t) {
          int tok = t * 16 + l15;
          f16x4 v = pk4(fmaf(aqk[ci][t][0], mult, bx), fmaf(aqk[ci][t][1], mult, by),
                        fmaf(aqk[ci][t][2], mult, bz), fmaf(aqk[ci][t][3], mult, bw));
          *(f16x4*)&smem[(gbase + tok * 25) * 8 + sub] = v;
        }
      }
    } else {
      const int cv0 = (wv - 12) * 3;
      f32x4 av[3][4];
#pragma unroll
      for (int ci = 0; ci < 3; ++ci)
#pragma unroll
        for (int t = 0; t < 4; ++t) av[ci][t] = zero4;
#pragma unroll
      for (int kc = 0; kc < 6; ++kc) {
        f16x8 xf[4];
#pragma unroll
        for (int t = 0; t < 4; ++t)
          xf[t] = *(const f16x8*)&smem[(G_XIN + (t * 16 + l15) * 25 + kc * 4 + lg) * 8];
        f16x8 w0, w1, w2;
        if (kc < 4) { w0 = wA[kc * 3]; w1 = wA[kc * 3 + 1]; w2 = wA[kc * 3 + 2]; }
        else        { w0 = wB[(kc - 4) * 3]; w1 = wB[(kc - 4) * 3 + 1]; w2 = wB[(kc - 4) * 3 + 2]; }
#pragma unroll
        for (int t = 0; t < 4; ++t) {
          av[0][t] = MFMA16(xf[t], w0, av[0][t]);
          av[1][t] = MFMA16(xf[t], w1, av[1][t]);
          av[2][t] = MFMA16(xf[t], w2, av[2][t]);
        }
      }
#pragma unroll
      for (int ci = 0; ci < 3; ++ci) {
        int vch = (cv0 + ci) * 16 + l15;
#pragma unroll
        for (int t = 0; t < 4; ++t) {
          f16x4 v = pk4(av[ci][t][0] + bv3[ci], av[ci][t][1] + bv3[ci],
                        av[ci][t][2] + bv3[ci], av[ci][t][3] + bv3[ci]);
          *(f16x4*)&smem[(G_VT + vch * 9 + 2 * t + (lg >> 1)) * 8 + (lg & 1) * 4] = v;
        }
      }
    }
    __syncthreads();   // barrier 1: q/k/vT ready; XIN dead

    // ---- issue next-window x loads (latency hides under phase 2) ----
    float4 xa0, xb0, xa1, xb1;
    if (it < 15) {
      int wjn = wj + 1;
      if (t0 < 49) {
        int hh = wi * 7 + t0 / 7 + 3; if (hh >= 448) hh -= 448;
        int ww = wjn * 7 + t0 % 7 + 3; if (ww >= 448) ww -= 448;
        const float4* s = (const float4*)(x + (size_t)(hh * 448 + ww) * 192 + g0 * 8);
        xa0 = s[0]; xb0 = s[1];
      }
      if (tid < 512 && t1 < 49) {
        int hh = wi * 7 + t1 / 7 + 3; if (hh >= 448) hh -= 448;
        int ww = wjn * 7 + t1 % 7 + 3; if (ww >= 448) ww -= 448;
        const float4* s = (const float4*)(x + (size_t)(hh * 448 + ww) * 192 + g1 * 8);
        xa1 = s[0]; xb1 = s[1];
      }
    }

    // ---------------- Phase 2: attention (no global accesses) ---------------
    if (hi < 2) attn_fast<2>(smem, bb, h0, p, lg, l15, mbits, edge);
    else        attn_fast<1>(smem, bb, h0, p, lg, l15, mbits, edge);
    __syncthreads();   // barrier 2: O ready; P dead

    // ---------------- Phase 3: out-proj + XIN refill + scatter --------------
    f32x4 acc[4];
    if (wv < 12) {
#pragma unroll
      for (int t = 0; t < 4; ++t) acc[t] = zero4;
#pragma unroll
      for (int kc = 0; kc < 6; ++kc) {
        f16x8 a[4];
#pragma unroll
        for (int t = 0; t < 4; ++t)
          a[t] = *(const f16x8*)&smem[(G_O + (t * 16 + l15) * 25 + kc * 4 + lg) * 8];
#pragma unroll
        for (int t = 0; t < 4; ++t) acc[t] = MFMA16(a[t], wB[kc], acc[t]);
      }
    }
    // write next-window x into XIN (P region is dead now)
    if (it < 15) {
      f16x8 v0;
      if (t0 < 49) v0 = pk8(xa0, xb0);
      else {
#pragma unroll
        for (int e2 = 0; e2 < 8; ++e2) v0[e2] = (f16)0.0f;
      }
      *(f16x8*)&smem[(G_XIN + t0 * 25 + g0) * 8] = v0;
      if (tid < 512) {
        f16x8 v1;
        if (t1 < 49) v1 = pk8(xa1, xb1);
        else {
#pragma unroll
          for (int e2 = 0; e2 < 8; ++e2) v1[e2] = (f16)0.0f;
        }
        *(f16x8*)&smem[(G_XIN + t1 * 25 + g1) * 8] = v1;
      }
    }
    if (wv < 12) {
      const int rr = wi >> 4;
      const int lane_off = rr * 192 + wv * 16 + l15;
#pragma unroll
      for (int t = 0; t < 4; ++t) {
#pragma unroll
        for (int r = 0; r < 4; ++r) {
          int pp = t * 16 + lg * 4 + r;
          if (pp < 49) {
            __builtin_nontemporal_store(acc[t][r] + boutr, out + s_addr[pp] + lane_off);
          }
        }
      }
    }
    __syncthreads();   // barrier 3: XIN ready for next window; stores issued
  }
}

// ---------------- fallback (no workspace): round-12 non-persistent ----------
__global__ __launch_bounds__(1024, 1) void wmsa_fb(
    const float* __restrict__ x,
    const float* __restrict__ Wqkv,
    const float* __restrict__ bqkv,
    const float* __restrict__ relpos,
    const float* __restrict__ Wout,
    const float* __restrict__ bout,
    float* __restrict__ out)
{
  __shared__ __align__(16) f16 smem[10000 * 8];
  int* s_addr = (int*)&smem[G_ADDR * 8];

  const int tid = threadIdx.x;
  const int wi = blockIdx.x >> 6, wj = blockIdx.x & 63;
  const int wv = tid >> 6;
  const int l = tid & 63;
  const int l15 = l & 15, lg = l >> 4;
  const f32x4 zero4 = {0.f, 0.f, 0.f, 0.f};
  const float QMULT = 0.17677669529663687f * 1.4426950408889634f;

  if (tid < 64) {
    int val = 0;
    if (tid < 49) {
      int i2 = tid / 7, j2 = tid - i2 * 7;
      int y = (wi & 15) * 7 + i2 + 3;  if (y >= 112) y -= 112;
      int xc = wj * 7 + j2 + 3;        if (xc >= 448) xc -= 448;
      val = (y * 448 + xc) * 768;
    }
    s_addr[tid] = val;
  }
  for (int gid = tid; gid < 1536; gid += 1024) {
    int t = gid / 24, g = gid - t * 24;
    f16x8 v;
    if (t < 49) {
      int hh = wi * 7 + t / 7 + 3; if (hh >= 448) hh -= 448;
      int ww = wj * 7 + t % 7 + 3; if (ww >= 448) ww -= 448;
      v = cvt8z(x + (size_t)(hh * 448 + ww) * 192 + g * 8);
    } else {
#pragma unroll
      for (int e = 0; e < 8; ++e) v[e] = (f16)0.0f;
    }
    *(f16x8*)&smem[(G_XIN + t * 25 + g) * 8] = v;
  }
  __syncthreads();

  auto ldq = [&](int kc, int nt) {
    int n = nt * 16 + (l & 15), k = kc * 32 + (l >> 4) * 8;
    return cvt8(Wqkv + (size_t)n * 192 + k);
  };
  auto ldo = [&](int kc, int nt) {
    int n = nt * 16 + (l & 15), k = kc * 32 + (l >> 4) * 8;
    return cvt8(Wout + (size_t)n * 192 + k);
  };

  if (wv < 12) {
    f32x4 aqk[2][4];
#pragma unroll
    for (int ci = 0; ci < 2; ++ci)
#pragma unroll
      for (int t = 0; t < 4; ++t) aqk[ci][t] = zero4;
#pragma unroll
    for (int kc = 0; kc < 6; ++kc) {
      f16x8 xf[4];
#pragma unroll
      for (int t = 0; t < 4; ++t)
        xf[t] = *(const f16x8*)&smem[(G_XIN + (t * 16 + l15) * 25 + kc * 4 + lg) * 8];
      f16x8 wq0 = ldq(kc, 2 * wv), wq1 = ldq(kc, 2 * wv + 1);
#pragma unroll
      for (int t = 0; t < 4; ++t) aqk[0][t] = MFMA16(wq0, xf[t], aqk[0][t]);
#pragma unroll
      for (int t = 0; t < 4; ++t) aqk[1][t] = MFMA16(wq1, xf[t], aqk[1][t]);
    }
#pragma unroll
    for (int ci = 0; ci < 2; ++ci) {
      int c0 = (2 * wv + ci) * 16 + lg * 4;
      float4 b4 = *(const float4*)(bqkv + c0);
      int part = (c0 >= 192) ? 1 : 0;
      int ch = c0 - part * 192;
      float mult = part ? 1.0f : QMULT;
      float bx = b4.x * mult, by = b4.y * mult, bz = b4.z * mult, bw = b4.w * mult;
      int gbase = (part ? G_K : G_Q) + (ch >> 3);
      int sub = ch & 7;
#pragma unroll
      for (int t = 0; t < 4; ++t) {
        int tok = t * 16 + l15;
        f16x4 v = pk4(fmaf(aqk[ci][t][0], mult, bx), fmaf(aqk[ci][t][1], mult, by),
                      fmaf(aqk[ci][t][2], mult, bz), fmaf(aqk[ci][t][3], mult, bw));
        *(f16x4*)&smem[(gbase + tok * 25) * 8 + sub] = v;
      }
    }
  } else {
    const int cv0 = (wv - 12) * 3;
    f32x4 av[3][4];
#pragma unroll
    for (int ci = 0; ci < 3; ++ci)
#pragma unroll
      for (int t = 0; t < 4; ++t) av[ci][t] = zero4;
#pragma unroll
    for (int kc = 0; kc < 6; ++kc) {
      f16x8 xf[4];
#pragma unroll
      for (int t = 0; t < 4; ++t)
        xf[t] = *(const f16x8*)&smem[(G_XIN + (t * 16 + l15) * 25 + kc * 4 + lg) * 8];
      f16x8 w0 = ldq(kc, 24 + cv0), w1 = ldq(kc, 24 + cv0 + 1), w2 = ldq(kc, 24 + cv0 + 2);
#pragma unroll
      for (int t = 0; t < 4; ++t) {
        av[0][t] = MFMA16(xf[t], w0, av[0][t]);
        av[1][t] = MFMA16(xf[t], w1, av[1][t]);
        av[2][t] = MFMA16(xf[t], w2, av[2][t]);
      }
    }
#pragma unroll
    for (int ci = 0; ci < 3; ++ci) {
      int vch = (cv0 + ci) * 16 + l15;
      float bv_ = bqkv[384 + vch];
#pragma unroll
      for (int t = 0; t < 4; ++t) {
        f16x4 v = pk4(av[ci][t][0] + bv_, av[ci][t][1] + bv_,
                      av[ci][t][2] + bv_, av[ci][t][3] + bv_);
        *(f16x4*)&smem[(G_VT + vch * 9 + 2 * t + (lg >> 1)) * 8 + (lg & 1) * 4] = v;
      }
    }
  }
  __syncthreads();

  {
    const int pt = wv & 3, hi = wv >> 2;
    const int h_first = (hi < 2) ? (hi * 2) : (hi + 2);
    const int h_count = (hi < 2) ? 2 : 1;
    const int p = 16 * pt + l15;
    const int pi = p / 7, pj = p - pi * 7;
    unsigned mbits = 0;
    int moff[16];
    float gaus[16];
#pragma unroll
    for (int jq = 0; jq < 4; ++jq)
#pragma unroll
      for (int r = 0; r < 4; ++r) {
        int q = 16 * jq + lg * 4 + r;
        int qi = q / 7, qj = q - qi * 7;
        int di = pi - qi, dj = pj - qj;
        bool bad = (q >= 49) || (p >= 49) ||
                   ((wi == 63) && ((pi < 4) != (qi < 4))) ||
                   ((wj == 63) && ((pj < 4) != (qj < 4)));
        int idx = jq * 4 + r;
        moff[idx] = bad ? 0 : (di + 6) * 13 + (dj + 6);
        gaus[idx] = __expf((float)(di * di + dj * dj) * (-9.0f / 98.0f));
        if (bad) mbits |= (1u << idx);
      }
    for (int e = 0; e < h_count; ++e) {
      int h = h_first + e;
      f16x8 aq = *(const f16x8*)&smem[(G_Q + p * 25 + h * 4 + lg) * 8];
      f32x4 sc[4];
#pragma unroll
      for (int jq = 0; jq < 4; ++jq) {
        f16x8 bk = *(const f16x8*)&smem[(G_K + (16 * jq + l15) * 25 + h * 4 + lg) * 8];
        sc[jq] = MFMA16(bk, aq, zero4);
      }
      float sv[16];
      float sum = 0.0f;
#pragma unroll
      for (int jq = 0; jq < 4; ++jq)
#pragma unroll
        for (int r = 0; r < 4; ++r) {
          int idx = jq * 4 + r;
          float s = (mbits >> idx & 1u)
              ? -30000.0f
              : sc[jq][r] + (relpos[h * 169 + moff[idx]] + gaus[idx]) * 1.4426950408889634f;
          float ev = fast_exp2(s);
          sv[idx] = ev;
          sum += ev;
        }
#pragma unroll
      for (int jq = 0; jq < 4; ++jq) {
        f16x4 v = pk4(sv[jq * 4], sv[jq * 4 + 1], sv[jq * 4 + 2], sv[jq * 4 + 3]);
        *(f16x4*)&smem[(G_P + h * 576 + p * 9 + 2 * jq + (lg >> 1)) * 8 + (lg & 1) * 4] = v;
      }
      sum += __shfl_xor(sum, 16);
      sum += __shfl_xor(sum, 32);
      float inv = __builtin_amdgcn_rcpf(sum);
      f32x4 o[2] = {zero4, zero4};
#pragma unroll
      for (int kq = 0; kq < 2; ++kq) {
        f16x8 ap = *(const f16x8*)&smem[(G_P + h * 576 + p * 9 + kq * 4 + lg) * 8];
#pragma unroll
        for (int jn = 0; jn < 2; ++jn) {
          int ch = h * 32 + jn * 16 + l15;
          f16x8 bv = *(const f16x8*)&smem[(G_VT + ch * 9 + kq * 4 + lg) * 8];
          o[jn] = MFMA16(bv, ap, o[jn]);
        }
      }
#pragma unroll
      for (int jn = 0; jn < 2; ++jn) {
        int ch0 = h * 32 + jn * 16 + lg * 4;
        f16x4 v = pk4(o[jn][0] * inv, o[jn][1] * inv, o[jn][2] * inv, o[jn][3] * inv);
        *(f16x4*)&smem[(G_O + p * 25 + (ch0 >> 3)) * 8 + (ch0 & 7)] = v;
      }
    }
  }
  __syncthreads();

  if (wv < 12) {
    const int ct = wv;
    f32x4 acc[4];
#pragma unroll
    for (int t = 0; t < 4; ++t) acc[t] = zero4;
#pragma unroll
    for (int kc = 0; kc < 6; ++kc) {
      f16x8 b = ldo(kc, ct);
      f16x8 a[4];
#pragma unroll
      for (int t = 0; t < 4; ++t)
        a[t] = *(const f16x8*)&smem[(G_O + (t * 16 + l15) * 25 + kc * 4 + lg) * 8];
#pragma unroll
      for (int t = 0; t < 4; ++t) acc[t] = MFMA16(a[t], b, acc[t]);
    }
    const int rr = wi >> 4;
    const int lane_off = rr * 192 + ct * 16 + l15;
    const float bias = bout[ct * 16 + l15];
#pragma unroll
    for (int t = 0; t < 4; ++t)
#pragma unroll
      for (int r = 0; r < 4; ++r) {
        int pp = t * 16 + lg * 4 + r;
        if (pp < 49)
          __builtin_nontemporal_store(acc[t][r] + bias, out + s_addr[pp] + lane_off);
      }
  }
}

extern "C" void kernel_launch(void* const* d_in, const int* in_sizes, int n_in,
                              void* d_out, int out_size, void* d_ws, size_t ws_size,
                              hipStream_t stream) {
  const float* x      = (const float*)d_in[0];
  const float* Wqkv   = (const float*)d_in[1];
  const float* bqkv   = (const float*)d_in[2];
  const float* relpos = (const float*)d_in[3];
  const float* Wout   = (const float*)d_in[4];
  const float* bout   = (const float*)d_in[5];
  float* out = (float*)d_out;
  f16* ws = (f16*)d_ws;

  if (ws_size >= (size_t)WS_NEED) {
    wmsa_prep<<<72, 256, 0, stream>>>(Wqkv, Wout, ws);
    wmsa_pers<<<256, 1024, 0, stream>>>(x, bqkv, relpos, bout, ws, out);
  } else {
    wmsa_fb<<<4096, 1024, 0, stream>>>(x, Wqkv, bqkv, relpos, Wout, bout, out);
  }
}

// Round 14
// 694.965 us; speedup vs baseline: 1.1753x; 1.1753x over previous
//
#include <hip/hip_runtime.h>

typedef _Float16 f16;
typedef _Float16 f16x8 __attribute__((ext_vector_type(8)));
typedef _Float16 f16x4 __attribute__((ext_vector_type(4)));
typedef _Float16 f16x2 __attribute__((ext_vector_type(2)));
typedef float f32x4 __attribute__((ext_vector_type(4)));

#define MFMA16(a, b, c) __builtin_amdgcn_mfma_f32_16x16x32_f16(a, b, c, 0, 0, 0)

// ws layout (f16 elems): [0,110592) Wqkv frags | [110592,147456) Wout frags
#define WS_NEED 294912   // bytes

// LDS arena granule (16 B) offsets — total 10000 granules = 160000 B
#define G_Q    0      // q  [64 tok][25g]
#define G_K    1600   // k  [64 tok][25g]
#define G_VT   3200   // v^T [192 ch][9g]
#define G_O    4928   // attn out [64 tok][25g]
#define G_P    6528   // P: 6 regions x 576g (aliases x-input staging)
#define G_XIN  6528   // x window [64 tok][25g] (dead after phase 1)
#define G_ADDR 9984   // int[64] scatter LUT

__device__ __forceinline__ float fast_exp2(float x) {
#if __has_builtin(__builtin_amdgcn_exp2f)
  return __builtin_amdgcn_exp2f(x);
#else
  float r;
  asm("v_exp_f32 %0, %1" : "=v"(r) : "v"(x));
  return r;
#endif
}

__device__ __forceinline__ f16x2 pkcvt(float a, float b) {
  auto r = __builtin_amdgcn_cvt_pkrtz(a, b);
  union { decltype(r) i; f16x2 o; } u;
  u.i = r;
  return u.o;
}

__device__ __forceinline__ f16x4 pk4(float a, float b, float c, float d) {
  union { f16x2 h2[2]; f16x4 h4; } u;
  u.h2[0] = pkcvt(a, b);
  u.h2[1] = pkcvt(c, d);
  return u.h4;
}

__device__ __forceinline__ f16x8 pk8(float4 a, float4 b) {
  union { f16x2 h2[4]; f16x8 h8; } u;
  u.h2[0] = pkcvt(a.x, a.y);
  u.h2[1] = pkcvt(a.z, a.w);
  u.h2[2] = pkcvt(b.x, b.y);
  u.h2[3] = pkcvt(b.z, b.w);
  return u.h8;
}

__device__ __forceinline__ f16x8 cvt8z(const float* p) {
  const float4* s = (const float4*)p;
  return pk8(s[0], s[1]);
}

__device__ __forceinline__ f16x8 cvt8(const float* p) {
  const float4* s = (const float4*)p;
  float4 u0 = s[0], u1 = s[1];
  f16x8 v;
  v[0] = (f16)u0.x; v[1] = (f16)u0.y; v[2] = (f16)u0.z; v[3] = (f16)u0.w;
  v[4] = (f16)u1.x; v[5] = (f16)u1.y; v[6] = (f16)u1.z; v[7] = (f16)u1.w;
  return v;
}

// ---- prep: W frags (f16, RTE) ----
__global__ void wmsa_prep(const float* __restrict__ Wqkv,
                          const float* __restrict__ Wout,
                          f16* __restrict__ ws) {
  int gid = blockIdx.x * 256 + threadIdx.x;
  if (gid < 13824) {
    int fb = gid >> 6, l = gid & 63;
    int kc = fb / 36, nt = fb - kc * 36;
    int n = nt * 16 + (l & 15), k = kc * 32 + (l >> 4) * 8;
    *(f16x8*)(ws + (size_t)gid * 8) = cvt8(Wqkv + (size_t)n * 192 + k);
  } else if (gid < 18432) {
    int g2 = gid - 13824;
    int fb = g2 >> 6, l = g2 & 63;
    int kc = fb / 12, nt = fb - kc * 12;
    int n = nt * 16 + (l & 15), k = kc * 32 + (l >> 4) * 8;
    *(f16x8*)(ws + 110592 + (size_t)g2 * 8) = cvt8(Wout + (size_t)n * 192 + k);
  }
}

// NH heads, interleaved chains, no-max softmax, f16 REGISTER bias.
template <int NH>
__device__ __forceinline__ void attn_fast(
    f16* smem, const f16x4 (&bb)[2][4], int h0,
    int p, int lg, int l15, unsigned mbits, bool edge)
{
  const f32x4 zero4 = {0.f, 0.f, 0.f, 0.f};
  f16x8 aq[NH];
#pragma unroll
  for (int e = 0; e < NH; ++e)
    aq[e] = *(const f16x8*)&smem[(G_Q + p * 25 + (h0 + e) * 4 + lg) * 8];
  f32x4 sc[NH][4];
  __builtin_amdgcn_s_setprio(1);
#pragma unroll
  for (int e = 0; e < NH; ++e)
#pragma unroll
    for (int jq = 0; jq < 4; ++jq) {
      f16x8 bk = *(const f16x8*)&smem[(G_K + (16 * jq + l15) * 25 + (h0 + e) * 4 + lg) * 8];
      sc[e][jq] = MFMA16(bk, aq[e], zero4);
    }
  __builtin_amdgcn_s_setprio(0);

  float sv[NH][16];
#pragma unroll
  for (int e = 0; e < NH; ++e) {
    if (!edge) {
#pragma unroll
      for (int jq = 0; jq < 4; ++jq)
#pragma unroll
        for (int r = 0; r < 4; ++r)
          sv[e][jq * 4 + r] = fast_exp2(sc[e][jq][r] + (float)bb[e][jq][r]);
    } else {
#pragma unroll
      for (int jq = 0; jq < 4; ++jq)
#pragma unroll
        for (int r = 0; r < 4; ++r) {
          int idx = jq * 4 + r;
          float s = (mbits >> idx & 1u) ? -30000.0f : sc[e][jq][r] + (float)bb[e][jq][r];
          sv[e][idx] = fast_exp2(s);
        }
    }
  }
#pragma unroll
  for (int e = 0; e < NH; ++e)
#pragma unroll
    for (int jq = 0; jq < 4; ++jq) {
      f16x4 v = pk4(sv[e][jq * 4], sv[e][jq * 4 + 1], sv[e][jq * 4 + 2], sv[e][jq * 4 + 3]);
      *(f16x4*)&smem[(G_P + (h0 + e) * 576 + p * 9 + 2 * jq + (lg >> 1)) * 8 + (lg & 1) * 4] = v;
    }
  float inv[NH];
#pragma unroll
  for (int e = 0; e < NH; ++e) {
    float s0 = (sv[e][0] + sv[e][1]) + (sv[e][2] + sv[e][3]);
    float s1 = (sv[e][4] + sv[e][5]) + (sv[e][6] + sv[e][7]);
    float s2 = (sv[e][8] + sv[e][9]) + (sv[e][10] + sv[e][11]);
    float s3 = (sv[e][12] + sv[e][13]) + (sv[e][14] + sv[e][15]);
    float sum = (s0 + s1) + (s2 + s3);
    sum += __shfl_xor(sum, 16);
    sum += __shfl_xor(sum, 32);
    inv[e] = __builtin_amdgcn_rcpf(sum);
  }
  f32x4 o[NH][2];
#pragma unroll
  for (int e = 0; e < NH; ++e) { o[e][0] = zero4; o[e][1] = zero4; }
  __builtin_amdgcn_s_setprio(1);
#pragma unroll
  for (int e = 0; e < NH; ++e)
#pragma unroll
    for (int kq = 0; kq < 2; ++kq) {
      f16x8 ap = *(const f16x8*)&smem[(G_P + (h0 + e) * 576 + p * 9 + kq * 4 + lg) * 8];
#pragma unroll
      for (int jn = 0; jn < 2; ++jn) {
        int ch = (h0 + e) * 32 + jn * 16 + l15;
        f16x8 bv = *(const f16x8*)&smem[(G_VT + ch * 9 + kq * 4 + lg) * 8];
        o[e][jn] = MFMA16(bv, ap, o[e][jn]);
      }
    }
  __builtin_amdgcn_s_setprio(0);
#pragma unroll
  for (int e = 0; e < NH; ++e)
#pragma unroll
    for (int jn = 0; jn < 2; ++jn) {
      int ch0 = (h0 + e) * 32 + jn * 16 + lg * 4;
      f16x4 v = pk4(o[e][jn][0] * inv[e], o[e][jn][1] * inv[e],
                    o[e][jn][2] * inv[e], o[e][jn][3] * inv[e]);
      *(f16x4*)&smem[(G_O + p * 25 + (ch0 >> 3)) * 8 + (ch0 & 7)] = v;
    }
}

// Persistent: 256 blocks x 1024 threads; block b handles windows b*16 .. +15.
// Weights from ws (L2) per iteration; bias/LUT/prefetch amortized.
__global__ __launch_bounds__(1024, 1) void wmsa_pers(
    const float* __restrict__ x,
    const float* __restrict__ bqkv,
    const float* __restrict__ relpos,
    const float* __restrict__ bout,
    const f16* __restrict__ ws,
    float* __restrict__ out)
{
  __shared__ __align__(16) f16 smem[10000 * 8];
  int* s_addr = (int*)&smem[G_ADDR * 8];

  const int tid = threadIdx.x;
  const int blk = blockIdx.x;
  const int wi = blk >> 2;
  const int wj0 = (blk & 3) * 16;
  const int wv = tid >> 6;
  const int l = tid & 63;
  const int l15 = l & 15, lg = l >> 4;
  const f32x4 zero4 = {0.f, 0.f, 0.f, 0.f};
  const float QMULT = 0.17677669529663687f * 1.4426950408889634f;

  // ---- resident softmax bias (f16, log2 domain) for this wave's heads ----
  const int pt = wv & 3, hi = wv >> 2;
  const int h0 = (hi < 2) ? hi * 2 : hi + 2;
  const int p = 16 * pt + l15;
  const int pi = p / 7, pj = p - pi * 7;
  f16x4 bbh[2][4];
#pragma unroll
  for (int e = 0; e < 2; ++e) {
    int h = h0 + ((hi < 2) ? e : 0);
#pragma unroll
    for (int jq = 0; jq < 4; ++jq) {
      float vv[4];
#pragma unroll
      for (int r = 0; r < 4; ++r) {
        int q = 16 * jq + lg * 4 + r;
        float v;
        if (q >= 49) v = -30000.0f;
        else if (p >= 49) v = 0.0f;
        else {
          int qi = q / 7, qj = q - qi * 7;
          int di = pi - qi, dj = pj - qj;
          float g = __expf((float)(di * di + dj * dj) * (-9.0f / 98.0f));
          v = (relpos[h * 169 + (di + 6) * 13 + (dj + 6)] + g) * 1.4426950408889634f;
        }
        vv[r] = v;
      }
      bbh[e][jq] = pk4(vv[0], vv[1], vv[2], vv[3]);
    }
  }

  // ---- loop-invariant proj biases ----
  float4 bq4[2];
  float bv3[3];
  float boutr = 0.0f;
  if (wv < 12) {
    bq4[0] = *(const float4*)(bqkv + (2 * wv) * 16 + lg * 4);
    bq4[1] = *(const float4*)(bqkv + (2 * wv + 1) * 16 + lg * 4);
    boutr = bout[wv * 16 + l15];
  } else {
    const int cv0 = (wv - 12) * 3;
    bv3[0] = bqkv[384 + (cv0 + 0) * 16 + l15];
    bv3[1] = bqkv[384 + (cv0 + 1) * 16 + l15];
    bv3[2] = bqkv[384 + (cv0 + 2) * 16 + l15];
  }

  // ---- prefetch thread mapping (loop-invariant) ----
  const int t0 = tid / 24, g0 = tid - t0 * 24;
  const int t1 = (tid + 1024) / 24, g1 = (tid + 1024) - t1 * 24;  // used when tid<512

  // ---- prologue: stage x for window it=0 ----
  for (int gid = tid; gid < 1536; gid += 1024) {
    int t = gid / 24, g = gid - t * 24;
    f16x8 v;
    if (t < 49) {
      int hh = wi * 7 + t / 7 + 3; if (hh >= 448) hh -= 448;
      int ww = wj0 * 7 + t % 7 + 3; if (ww >= 448) ww -= 448;
      v = cvt8z(x + (size_t)(hh * 448 + ww) * 192 + g * 8);
    } else {
#pragma unroll
      for (int e2 = 0; e2 < 8; ++e2) v[e2] = (f16)0.0f;
    }
    *(f16x8*)&smem[(G_XIN + t * 25 + g) * 8] = v;
  }
  __syncthreads();

  for (int it = 0; it < 16; ++it) {
    const int wj = wj0 + it;
    // scatter LUT for this window (read in phase 3, 2 barriers later)
    if (tid < 64) {
      int val = 0;
      if (tid < 49) {
        int i2 = tid / 7, j2 = tid - i2 * 7;
        int y = (wi & 15) * 7 + i2 + 3;  if (y >= 112) y -= 112;
        int xc = wj * 7 + j2 + 3;        if (xc >= 448) xc -= 448;
        val = (y * 448 + xc) * 768;
      }
      s_addr[tid] = val;
    }
    const bool edge = (wi == 63) || (wj == 63);
    unsigned mbits = 0;
    if (edge) {
#pragma unroll
      for (int jq = 0; jq < 4; ++jq)
#pragma unroll
        for (int r = 0; r < 4; ++r) {
          int q = 16 * jq + lg * 4 + r;
          int qi = q / 7, qj = q - qi * 7;
          bool bad = (q >= 49) || (p >= 49) ||
                     ((wi == 63) && ((pi < 4) != (qi < 4))) ||
                     ((wj == 63) && ((pj < 4) != (qj < 4)));
          if (bad) mbits |= (1u << (jq * 4 + r));
        }
    }

    // ---------------- Phase 1: QKV (weights from ws / L2) -------------------
    if (wv < 12) {
      f32x4 aqk[2][4];
#pragma unroll
      for (int ci = 0; ci < 2; ++ci)
#pragma unroll
        for (int t = 0; t < 4; ++t) aqk[ci][t] = zero4;
#pragma unroll
      for (int kc = 0; kc < 6; ++kc) {
        f16x8 xf[4];
#pragma unroll
        for (int t = 0; t < 4; ++t)
          xf[t] = *(const f16x8*)&smem[(G_XIN + (t * 16 + l15) * 25 + kc * 4 + lg) * 8];
        f16x8 wq0 = *(const f16x8*)(ws + (size_t)(kc * 36 + 2 * wv) * 512 + l * 8);
        f16x8 wq1 = *(const f16x8*)(ws + (size_t)(kc * 36 + 2 * wv + 1) * 512 + l * 8);
#pragma unroll
        for (int t = 0; t < 4; ++t) aqk[0][t] = MFMA16(wq0, xf[t], aqk[0][t]);
#pragma unroll
        for (int t = 0; t < 4; ++t) aqk[1][t] = MFMA16(wq1, xf[t], aqk[1][t]);
      }
#pragma unroll
      for (int ci = 0; ci < 2; ++ci) {
        int c0 = (2 * wv + ci) * 16 + lg * 4;
        int part = (c0 >= 192) ? 1 : 0;
        int ch = c0 - part * 192;
        float mult = part ? 1.0f : QMULT;
        float bx = bq4[ci].x * mult, by = bq4[ci].y * mult;
        float bz = bq4[ci].z * mult, bw = bq4[ci].w * mult;
        int gbase = (part ? G_K : G_Q) + (ch >> 3);
        int sub = ch & 7;
#pragma unroll
        for (int t = 0; t < 4; ++t) {
          int tok = t * 16 + l15;
          f16x4 v = pk4(fmaf(aqk[ci][t][0], mult, bx), fmaf(aqk[ci][t][1], mult, by),
                        fmaf(aqk[ci][t][2], mult, bz), fmaf(aqk[ci][t][3], mult, bw));
          *(f16x4*)&smem[(gbase + tok * 25) * 8 + sub] = v;
        }
      }
    } else {
      const int cv0 = (wv - 12) * 3;
      f32x4 av[3][4];
#pragma unroll
      for (int ci = 0; ci < 3; ++ci)
#pragma unroll
        for (int t = 0; t < 4; ++t) av[ci][t] = zero4;
#pragma unroll
      for (int kc = 0; kc < 6; ++kc) {
        f16x8 xf[4];
#pragma unroll
        for (int t = 0; t < 4; ++t)
          xf[t] = *(const f16x8*)&smem[(G_XIN + (t * 16 + l15) * 25 + kc * 4 + lg) * 8];
        f16x8 w0 = *(const f16x8*)(ws + (size_t)(kc * 36 + 24 + cv0) * 512 + l * 8);
        f16x8 w1 = *(const f16x8*)(ws + (size_t)(kc * 36 + 24 + cv0 + 1) * 512 + l * 8);
        f16x8 w2 = *(const f16x8*)(ws + (size_t)(kc * 36 + 24 + cv0 + 2) * 512 + l * 8);
#pragma unroll
        for (int t = 0; t < 4; ++t) {
          av[0][t] = MFMA16(xf[t], w0, av[0][t]);
          av[1][t] = MFMA16(xf[t], w1, av[1][t]);
          av[2][t] = MFMA16(xf[t], w2, av[2][t]);
        }
      }
#pragma unroll
      for (int ci = 0; ci < 3; ++ci) {
        int vch = (cv0 + ci) * 16 + l15;
#pragma unroll
        for (int t = 0; t < 4; ++t) {
          f16x4 v = pk4(av[ci][t][0] + bv3[ci], av[ci][t][1] + bv3[ci],
                        av[ci][t][2] + bv3[ci], av[ci][t][3] + bv3[ci]);
          *(f16x4*)&smem[(G_VT + vch * 9 + 2 * t + (lg >> 1)) * 8 + (lg & 1) * 4] = v;
        }
      }
    }
    __syncthreads();   // barrier 1: q/k/vT ready; XIN dead

    // ---- issue next-window x loads (latency hides under phase 2) ----
    float4 xa0, xb0, xa1, xb1;
    if (it < 15) {
      int wjn = wj + 1;
      if (t0 < 49) {
        int hh = wi * 7 + t0 / 7 + 3; if (hh >= 448) hh -= 448;
        int ww = wjn * 7 + t0 % 7 + 3; if (ww >= 448) ww -= 448;
        const float4* s = (const float4*)(x + (size_t)(hh * 448 + ww) * 192 + g0 * 8);
        xa0 = s[0]; xb0 = s[1];
      }
      if (tid < 512 && t1 < 49) {
        int hh = wi * 7 + t1 / 7 + 3; if (hh >= 448) hh -= 448;
        int ww = wjn * 7 + t1 % 7 + 3; if (ww >= 448) ww -= 448;
        const float4* s = (const float4*)(x + (size_t)(hh * 448 + ww) * 192 + g1 * 8);
        xa1 = s[0]; xb1 = s[1];
      }
    }

    // ---------------- Phase 2: attention (no global loads on path) ----------
    if (hi < 2) attn_fast<2>(smem, bbh, h0, p, lg, l15, mbits, edge);
    else        attn_fast<1>(smem, bbh, h0, p, lg, l15, mbits, edge);
    __syncthreads();   // barrier 2: O ready; P dead

    // ---------------- Phase 3: out-proj + XIN refill + scatter --------------
    f32x4 acc[4];
    if (wv < 12) {
#pragma unroll
      for (int t = 0; t < 4; ++t) acc[t] = zero4;
#pragma unroll
      for (int kc = 0; kc < 6; ++kc) {
        f16x8 b = *(const f16x8*)(ws + 110592 + (size_t)(kc * 12 + wv) * 512 + l * 8);
        f16x8 a[4];
#pragma unroll
        for (int t = 0; t < 4; ++t)
          a[t] = *(const f16x8*)&smem[(G_O + (t * 16 + l15) * 25 + kc * 4 + lg) * 8];
#pragma unroll
        for (int t = 0; t < 4; ++t) acc[t] = MFMA16(a[t], b, acc[t]);
      }
    }
    // write next-window x into XIN (P region dead now)
    if (it < 15) {
      f16x8 v0;
      if (t0 < 49) v0 = pk8(xa0, xb0);
      else {
#pragma unroll
        for (int e2 = 0; e2 < 8; ++e2) v0[e2] = (f16)0.0f;
      }
      *(f16x8*)&smem[(G_XIN + t0 * 25 + g0) * 8] = v0;
      if (tid < 512) {
        f16x8 v1;
        if (t1 < 49) v1 = pk8(xa1, xb1);
        else {
#pragma unroll
          for (int e2 = 0; e2 < 8; ++e2) v1[e2] = (f16)0.0f;
        }
        *(f16x8*)&smem[(G_XIN + t1 * 25 + g1) * 8] = v1;
      }
    }
    if (wv < 12) {
      const int rr = wi >> 4;
      const int lane_off = rr * 192 + wv * 16 + l15;
#pragma unroll
      for (int t = 0; t < 4; ++t) {
#pragma unroll
        for (int r = 0; r < 4; ++r) {
          int pp = t * 16 + lg * 4 + r;
          if (pp < 49) {
            __builtin_nontemporal_store(acc[t][r] + boutr, out + s_addr[pp] + lane_off);
          }
        }
      }
    }
    __syncthreads();   // barrier 3: XIN ready for next window
  }
}

// ---------------- fallback (no workspace): round-12 structure ---------------
__global__ __launch_bounds__(1024, 1) void wmsa_fb(
    const float* __restrict__ x,
    const float* __restrict__ Wqkv,
    const float* __restrict__ bqkv,
    const float* __restrict__ relpos,
    const float* __restrict__ Wout,
    const float* __restrict__ bout,
    float* __restrict__ out)
{
  __shared__ __align__(16) f16 smem[10000 * 8];
  int* s_addr = (int*)&smem[G_ADDR * 8];

  const int tid = threadIdx.x;
  const int wi = blockIdx.x >> 6, wj = blockIdx.x & 63;
  const int wv = tid >> 6;
  const int l = tid & 63;
  const int l15 = l & 15, lg = l >> 4;
  const f32x4 zero4 = {0.f, 0.f, 0.f, 0.f};
  const float QMULT = 0.17677669529663687f * 1.4426950408889634f;

  if (tid < 64) {
    int val = 0;
    if (tid < 49) {
      int i2 = tid / 7, j2 = tid - i2 * 7;
      int y = (wi & 15) * 7 + i2 + 3;  if (y >= 112) y -= 112;
      int xc = wj * 7 + j2 + 3;        if (xc >= 448) xc -= 448;
      val = (y * 448 + xc) * 768;
    }
    s_addr[tid] = val;
  }
  for (int gid = tid; gid < 1536; gid += 1024) {
    int t = gid / 24, g = gid - t * 24;
    f16x8 v;
    if (t < 49) {
      int hh = wi * 7 + t / 7 + 3; if (hh >= 448) hh -= 448;
      int ww = wj * 7 + t % 7 + 3; if (ww >= 448) ww -= 448;
      v = cvt8z(x + (size_t)(hh * 448 + ww) * 192 + g * 8);
    } else {
#pragma unroll
      for (int e = 0; e < 8; ++e) v[e] = (f16)0.0f;
    }
    *(f16x8*)&smem[(G_XIN + t * 25 + g) * 8] = v;
  }
  __syncthreads();

  auto ldq = [&](int kc, int nt) {
    int n = nt * 16 + (l & 15), k = kc * 32 + (l >> 4) * 8;
    return cvt8(Wqkv + (size_t)n * 192 + k);
  };
  auto ldo = [&](int kc, int nt) {
    int n = nt * 16 + (l & 15), k = kc * 32 + (l >> 4) * 8;
    return cvt8(Wout + (size_t)n * 192 + k);
  };

  if (wv < 12) {
    f32x4 aqk[2][4];
#pragma unroll
    for (int ci = 0; ci < 2; ++ci)
#pragma unroll
      for (int t = 0; t < 4; ++t) aqk[ci][t] = zero4;
#pragma unroll
    for (int kc = 0; kc < 6; ++kc) {
      f16x8 xf[4];
#pragma unroll
      for (int t = 0; t < 4; ++t)
        xf[t] = *(const f16x8*)&smem[(G_XIN + (t * 16 + l15) * 25 + kc * 4 + lg) * 8];
      f16x8 wq0 = ldq(kc, 2 * wv), wq1 = ldq(kc, 2 * wv + 1);
#pragma unroll
      for (int t = 0; t < 4; ++t) aqk[0][t] = MFMA16(wq0, xf[t], aqk[0][t]);
#pragma unroll
      for (int t = 0; t < 4; ++t) aqk[1][t] = MFMA16(wq1, xf[t], aqk[1][t]);
    }
#pragma unroll
    for (int ci = 0; ci < 2; ++ci) {
      int c0 = (2 * wv + ci) * 16 + lg * 4;
      float4 b4 = *(const float4*)(bqkv + c0);
      int part = (c0 >= 192) ? 1 : 0;
      int ch = c0 - part * 192;
      float mult = part ? 1.0f : QMULT;
      float bx = b4.x * mult, by = b4.y * mult, bz = b4.z * mult, bw = b4.w * mult;
      int gbase = (part ? G_K : G_Q) + (ch >> 3);
      int sub = ch & 7;
#pragma unroll
      for (int t = 0; t < 4; ++t) {
        int tok = t * 16 + l15;
        f16x4 v = pk4(fmaf(aqk[ci][t][0], mult, bx), fmaf(aqk[ci][t][1], mult, by),
                      fmaf(aqk[ci][t][2], mult, bz), fmaf(aqk[ci][t][3], mult, bw));
        *(f16x4*)&smem[(gbase + tok * 25) * 8 + sub] = v;
      }
    }
  } else {
    const int cv0 = (wv - 12) * 3;
    f32x4 av[3][4];
#pragma unroll
    for (int ci = 0; ci < 3; ++ci)
#pragma unroll
      for (int t = 0; t < 4; ++t) av[ci][t] = zero4;
#pragma unroll
    for (int kc = 0; kc < 6; ++kc) {
      f16x8 xf[4];
#pragma unroll
      for (int t = 0; t < 4; ++t)
        xf[t] = *(const f16x8*)&smem[(G_XIN + (t * 16 + l15) * 25 + kc * 4 + lg) * 8];
      f16x8 w0 = ldq(kc, 24 + cv0), w1 = ldq(kc, 24 + cv0 + 1), w2 = ldq(kc, 24 + cv0 + 2);
#pragma unroll
      for (int t = 0; t < 4; ++t) {
        av[0][t] = MFMA16(xf[t], w0, av[0][t]);
        av[1][t] = MFMA16(xf[t], w1, av[1][t]);
        av[2][t] = MFMA16(xf[t], w2, av[2][t]);
      }
    }
#pragma unroll
    for (int ci = 0; ci < 3; ++ci) {
      int vch = (cv0 + ci) * 16 + l15;
      float bv_ = bqkv[384 + vch];
#pragma unroll
      for (int t = 0; t < 4; ++t) {
        f16x4 v = pk4(av[ci][t][0] + bv_, av[ci][t][1] + bv_,
                      av[ci][t][2] + bv_, av[ci][t][3] + bv_);
        *(f16x4*)&smem[(G_VT + vch * 9 + 2 * t + (lg >> 1)) * 8 + (lg & 1) * 4] = v;
      }
    }
  }
  __syncthreads();

  {
    const int pt = wv & 3, hi = wv >> 2;
    const int h_first = (hi < 2) ? (hi * 2) : (hi + 2);
    const int h_count = (hi < 2) ? 2 : 1;
    const int p = 16 * pt + l15;
    const int pi = p / 7, pj = p - pi * 7;
    unsigned mbits = 0;
    int moff[16];
    float gaus[16];
#pragma unroll
    for (int jq = 0; jq < 4; ++jq)
#pragma unroll
      for (int r = 0; r < 4; ++r) {
        int q = 16 * jq + lg * 4 + r;
        int qi = q / 7, qj = q - qi * 7;
        int di = pi - qi, dj = pj - qj;
        bool bad = (q >= 49) || (p >= 49) ||
                   ((wi == 63) && ((pi < 4) != (qi < 4))) ||
                   ((wj == 63) && ((pj < 4) != (qj < 4)));
        int idx = jq * 4 + r;
        moff[idx] = bad ? 0 : (di + 6) * 13 + (dj + 6);
        gaus[idx] = __expf((float)(di * di + dj * dj) * (-9.0f / 98.0f));
        if (bad) mbits |= (1u << idx);
      }
    for (int e = 0; e < h_count; ++e) {
      int h = h_first + e;
      f16x8 aq = *(const f16x8*)&smem[(G_Q + p * 25 + h * 4 + lg) * 8];
      f32x4 sc[4];
#pragma unroll
      for (int jq = 0; jq < 4; ++jq) {
        f16x8 bk = *(const f16x8*)&smem[(G_K + (16 * jq + l15) * 25 + h * 4 + lg) * 8];
        sc[jq] = MFMA16(bk, aq, zero4);
      }
      float sv[16];
      float sum = 0.0f;
#pragma unroll
      for (int jq = 0; jq < 4; ++jq)
#pragma unroll
        for (int r = 0; r < 4; ++r) {
          int idx = jq * 4 + r;
          float s = (mbits >> idx & 1u)
              ? -30000.0f
              : sc[jq][r] + (relpos[h * 169 + moff[idx]] + gaus[idx]) * 1.4426950408889634f;
          float ev = fast_exp2(s);
          sv[idx] = ev;
          sum += ev;
        }
#pragma unroll
      for (int jq = 0; jq < 4; ++jq) {
        f16x4 v = pk4(sv[jq * 4], sv[jq * 4 + 1], sv[jq * 4 + 2], sv[jq * 4 + 3]);
        *(f16x4*)&smem[(G_P + h * 576 + p * 9 + 2 * jq + (lg >> 1)) * 8 + (lg & 1) * 4] = v;
      }
      sum += __shfl_xor(sum, 16);
      sum += __shfl_xor(sum, 32);
      float inv = __builtin_amdgcn_rcpf(sum);
      f32x4 o[2] = {zero4, zero4};
#pragma unroll
      for (int kq = 0; kq < 2; ++kq) {
        f16x8 ap = *(const f16x8*)&smem[(G_P + h * 576 + p * 9 + kq * 4 + lg) * 8];
#pragma unroll
        for (int jn = 0; jn < 2; ++jn) {
          int ch = h * 32 + jn * 16 + l15;
          f16x8 bv = *(const f16x8*)&smem[(G_VT + ch * 9 + kq * 4 + lg) * 8];
          o[jn] = MFMA16(bv, ap, o[jn]);
        }
      }
#pragma unroll
      for (int jn = 0; jn < 2; ++jn) {
        int ch0 = h * 32 + jn * 16 + lg * 4;
        f16x4 v = pk4(o[jn][0] * inv, o[jn][1] * inv, o[jn][2] * inv, o[jn][3] * inv);
        *(f16x4*)&smem[(G_O + p * 25 + (ch0 >> 3)) * 8 + (ch0 & 7)] = v;
      }
    }
  }
  __syncthreads();

  if (wv < 12) {
    const int ct = wv;
    f32x4 acc[4];
#pragma unroll
    for (int t = 0; t < 4; ++t) acc[t] = zero4;
#pragma unroll
    for (int kc = 0; kc < 6; ++kc) {
      f16x8 b = ldo(kc, ct);
      f16x8 a[4];
#pragma unroll
      for (int t = 0; t < 4; ++t)
        a[t] = *(const f16x8*)&smem[(G_O + (t * 16 + l15) * 25 + kc * 4 + lg) * 8];
#pragma unroll
      for (int t = 0; t < 4; ++t) acc[t] = MFMA16(a[t], b, acc[t]);
    }
    const int rr = wi >> 4;
    const int lane_off = rr * 192 + ct * 16 + l15;
    const float bias = bout[ct * 16 + l15];
#pragma unroll
    for (int t = 0; t < 4; ++t)
#pragma unroll
      for (int r = 0; r < 4; ++r) {
        int pp = t * 16 + lg * 4 + r;
        if (pp < 49)
          __builtin_nontemporal_store(acc[t][r] + bias, out + s_addr[pp] + lane_off);
      }
  }
}

extern "C" void kernel_launch(void* const* d_in, const int* in_sizes, int n_in,
                              void* d_out, int out_size, void* d_ws, size_t ws_size,
                              hipStream_t stream) {
  const float* x      = (const float*)d_in[0];
  const float* Wqkv   = (const float*)d_in[1];
  const float* bqkv   = (const float*)d_in[2];
  const float* relpos = (const float*)d_in[3];
  const float* Wout   = (const float*)d_in[4];
  const float* bout   = (const float*)d_in[5];
  float* out = (float*)d_out;
  f16* ws = (f16*)d_ws;

  if (ws_size >= (size_t)WS_NEED) {
    wmsa_prep<<<72, 256, 0, stream>>>(Wqkv, Wout, ws);
    wmsa_pers<<<256, 1024, 0, stream>>>(x, bqkv, relpos, bout, ws, out);
  } else {
    wmsa_fb<<<4096, 1024, 0, stream>>>(x, Wqkv, bqkv, relpos, Wout, bout, out);
  }
}

// Round 15
// 158.357 us; speedup vs baseline: 5.1581x; 4.3886x over previous
//
#include <hip/hip_runtime.h>

typedef _Float16 f16;
typedef _Float16 f16x8 __attribute__((ext_vector_type(8)));
typedef _Float16 f16x4 __attribute__((ext_vector_type(4)));
typedef _Float16 f16x2 __attribute__((ext_vector_type(2)));
typedef float f32x4 __attribute__((ext_vector_type(4)));

#define MFMA16(a, b, c) __builtin_amdgcn_mfma_f32_16x16x32_f16(a, b, c, 0, 0, 0)

// ws layout (f16 elems): [0,110592) Wqkv frags | [110592,147456) Wout frags
//                        [147456, 147456+26112) f16 bias table [6][64][68]
#define WS_BIAS_ELEM 147456
#define WS_NEED (294912 + 52224)

// LDS arena granule (16 B) offsets — total 10000 granules = 160000 B
#define G_Q    0      // q  [64 tok][25g]
#define G_K    1600   // k  [64 tok][25g]
#define G_VT   3200   // v^T [192 ch][9g]
#define G_O    4928   // attn out [64 tok][25g]
#define G_P    6528   // P: 6 regions x 576g (aliases x-input staging)
#define G_XIN  6528   // x window [64 tok][25g] (dead after phase 1)
#define G_ADDR 9984   // int[64] scatter LUT

__device__ __forceinline__ float fast_exp2(float x) {
#if __has_builtin(__builtin_amdgcn_exp2f)
  return __builtin_amdgcn_exp2f(x);
#else
  float r;
  asm("v_exp_f32 %0, %1" : "=v"(r) : "v"(x));
  return r;
#endif
}

__device__ __forceinline__ f16x2 pkcvt(float a, float b) {
  auto r = __builtin_amdgcn_cvt_pkrtz(a, b);
  union { decltype(r) i; f16x2 o; } u;
  u.i = r;
  return u.o;
}

__device__ __forceinline__ f16x4 pk4(float a, float b, float c, float d) {
  union { f16x2 h2[2]; f16x4 h4; } u;
  u.h2[0] = pkcvt(a, b);
  u.h2[1] = pkcvt(c, d);
  return u.h4;
}

__device__ __forceinline__ f16x8 cvt8z(const float* p) {
  const float4* s = (const float4*)p;
  float4 u0 = s[0], u1 = s[1];
  union { f16x2 h2[4]; f16x8 h8; } u;
  u.h2[0] = pkcvt(u0.x, u0.y);
  u.h2[1] = pkcvt(u0.z, u0.w);
  u.h2[2] = pkcvt(u1.x, u1.y);
  u.h2[3] = pkcvt(u1.z, u1.w);
  return u.h8;
}

__device__ __forceinline__ f16x8 cvt8(const float* p) {
  const float4* s = (const float4*)p;
  float4 u0 = s[0], u1 = s[1];
  f16x8 v;
  v[0] = (f16)u0.x; v[1] = (f16)u0.y; v[2] = (f16)u0.z; v[3] = (f16)u0.w;
  v[4] = (f16)u1.x; v[5] = (f16)u1.y; v[6] = (f16)u1.z; v[7] = (f16)u1.w;
  return v;
}

// ---- prep: W frags (f16, RTE) + f16 bias table ----
__global__ void wmsa_prep(const float* __restrict__ Wqkv,
                          const float* __restrict__ Wout,
                          const float* __restrict__ relpos,
                          f16* __restrict__ ws) {
  int gid = blockIdx.x * 256 + threadIdx.x;
  if (gid < 13824) {
    int fb = gid >> 6, l = gid & 63;
    int kc = fb / 36, nt = fb - kc * 36;
    int n = nt * 16 + (l & 15), k = kc * 32 + (l >> 4) * 8;
    *(f16x8*)(ws + (size_t)gid * 8) = cvt8(Wqkv + (size_t)n * 192 + k);
  } else if (gid < 18432) {
    int g2 = gid - 13824;
    int fb = g2 >> 6, l = g2 & 63;
    int kc = fb / 12, nt = fb - kc * 12;
    int n = nt * 16 + (l & 15), k = kc * 32 + (l >> 4) * 8;
    *(f16x8*)(ws + 110592 + (size_t)g2 * 8) = cvt8(Wout + (size_t)n * 192 + k);
  } else if (gid < 18432 + 26112) {
    int g3 = gid - 18432;                  // [6][64 p][68 q]
    int h = g3 / 4352, rem = g3 - h * 4352;
    int p = rem / 68, q = rem - p * 68;
    float v = 0.0f;
    if (q >= 49) v = -30000.0f;
    else if (p < 49) {
      int pi = p / 7, pj = p - pi * 7;
      int qi = q / 7, qj = q - qi * 7;
      int di = pi - qi, dj = pj - qj;
      float g = __expf((float)(di * di + dj * dj) * (-9.0f / 98.0f));
      v = (relpos[h * 169 + (di + 6) * 13 + (dj + 6)] + g) * 1.4426950408889634f;
    }
    ws[WS_BIAS_ELEM + g3] = (f16)v;
  }
}

template <bool USE_WS>
__device__ __forceinline__ f16x8 load_bq(const f16* wsq, const float* Wqkv,
                                         int kc, int nt, int l) {
  if constexpr (USE_WS) {
    return *(const f16x8*)(wsq + (size_t)(kc * 36 + nt) * 512 + l * 8);
  } else {
    int n = nt * 16 + (l & 15), k = kc * 32 + (l >> 4) * 8;
    return cvt8(Wqkv + (size_t)n * 192 + k);
  }
}

template <bool USE_WS>
__device__ __forceinline__ f16x8 load_bo(const f16* wsq, const float* Wout,
                                         int kc, int nt, int l) {
  if constexpr (USE_WS) {
    return *(const f16x8*)(wsq + 110592 + (size_t)(kc * 12 + nt) * 512 + l * 8);
  } else {
    int n = nt * 16 + (l & 15), k = kc * 32 + (l >> 4) * 8;
    return cvt8(Wout + (size_t)n * 192 + k);
  }
}

// NH heads, interleaved independent chains, no-max softmax, f16 bias table.
template <int NH>
__device__ __forceinline__ void attn_fast(
    f16* smem, const f16* bb_base, int h0,
    int p, int lg, int l15, unsigned mbits, bool edge)
{
  const f32x4 zero4 = {0.f, 0.f, 0.f, 0.f};
  // loop-invariant LDS bases
  const int qrow = (G_Q + p * 25 + lg) * 8;
  const int prow = p * 9 * 8;
  f16x8 aq[NH];
#pragma unroll
  for (int e = 0; e < NH; ++e)
    aq[e] = *(const f16x8*)&smem[qrow + (h0 + e) * 32];
  f32x4 sc[NH][4];
  __builtin_amdgcn_s_setprio(1);
#pragma unroll
  for (int e = 0; e < NH; ++e)
#pragma unroll
    for (int jq = 0; jq < 4; ++jq) {
      f16x8 bk = *(const f16x8*)&smem[(G_K + (16 * jq + l15) * 25 + (h0 + e) * 4 + lg) * 8];
      sc[e][jq] = MFMA16(bk, aq[e], zero4);
    }
  __builtin_amdgcn_s_setprio(0);

  float sv[NH][16];
#pragma unroll
  for (int e = 0; e < NH; ++e) {
    if (!edge) {
#pragma unroll
      for (int jq = 0; jq < 4; ++jq) {
        f16x4 bb4 = *(const f16x4*)(bb_base + (h0 + e) * 4352 + 16 * jq);
#pragma unroll
        for (int r = 0; r < 4; ++r)
          sv[e][jq * 4 + r] = fast_exp2(sc[e][jq][r] + (float)bb4[r]);
      }
    } else {
#pragma unroll
      for (int jq = 0; jq < 4; ++jq) {
        f16x4 bb4 = *(const f16x4*)(bb_base + (h0 + e) * 4352 + 16 * jq);
#pragma unroll
        for (int r = 0; r < 4; ++r) {
          int idx = jq * 4 + r;
          float s = (mbits >> idx & 1u) ? -30000.0f : sc[e][jq][r] + (float)bb4[r];
          sv[e][idx] = fast_exp2(s);
        }
      }
    }
  }
  // store UNNORMALIZED P (per-head region: no cross-head hazard)
#pragma unroll
  for (int e = 0; e < NH; ++e)
#pragma unroll
    for (int jq = 0; jq < 4; ++jq) {
      f16x4 v = pk4(sv[e][jq * 4], sv[e][jq * 4 + 1], sv[e][jq * 4 + 2], sv[e][jq * 4 + 3]);
      *(f16x4*)&smem[(G_P + (h0 + e) * 576) * 8 + prow + (2 * jq + (lg >> 1)) * 8 + (lg & 1) * 4] = v;
    }
  // tree-sum denominator (depth 4), then cross-lane reduce
  float inv[NH];
#pragma unroll
  for (int e = 0; e < NH; ++e) {
    float s0 = (sv[e][0] + sv[e][1]) + (sv[e][2] + sv[e][3]);
    float s1 = (sv[e][4] + sv[e][5]) + (sv[e][6] + sv[e][7]);
    float s2 = (sv[e][8] + sv[e][9]) + (sv[e][10] + sv[e][11]);
    float s3 = (sv[e][12] + sv[e][13]) + (sv[e][14] + sv[e][15]);
    float sum = (s0 + s1) + (s2 + s3);
    sum += __shfl_xor(sum, 16);
    sum += __shfl_xor(sum, 32);
    inv[e] = __builtin_amdgcn_rcpf(sum);
  }
  f32x4 o[NH][2];
#pragma unroll
  for (int e = 0; e < NH; ++e) { o[e][0] = zero4; o[e][1] = zero4; }
  __builtin_amdgcn_s_setprio(1);
#pragma unroll
  for (int e = 0; e < NH; ++e)
#pragma unroll
    for (int kq = 0; kq < 2; ++kq) {
      f16x8 ap = *(const f16x8*)&smem[(G_P + (h0 + e) * 576) * 8 + prow + (kq * 4 + lg) * 8];
#pragma unroll
      for (int jn = 0; jn < 2; ++jn) {
        int ch = (h0 + e) * 32 + jn * 16 + l15;
        f16x8 bv = *(const f16x8*)&smem[(G_VT + ch * 9 + kq * 4 + lg) * 8];
        o[e][jn] = MFMA16(bv, ap, o[e][jn]);
      }
    }
  __builtin_amdgcn_s_setprio(0);
#pragma unroll
  for (int e = 0; e < NH; ++e)
#pragma unroll
    for (int jn = 0; jn < 2; ++jn) {
      int ch0 = (h0 + e) * 32 + jn * 16 + lg * 4;
      f16x4 v = pk4(o[e][jn][0] * inv[e], o[e][jn][1] * inv[e],
                    o[e][jn][2] * inv[e], o[e][jn][3] * inv[e]);
      *(f16x4*)&smem[(G_O + p * 25 + (ch0 >> 3)) * 8 + (ch0 & 7)] = v;
    }
}

// One block per 7x7 window, 1024 threads = 16 waves = 4 waves/SIMD.
template <bool USE_WS>
__global__ __launch_bounds__(1024, 1) void wmsa_main(
    const float* __restrict__ x,
    const float* __restrict__ Wqkv,
    const float* __restrict__ bqkv,
    const float* __restrict__ relpos,
    const float* __restrict__ Wout,
    const float* __restrict__ bout,
    const f16* __restrict__ ws,
    float* __restrict__ out)
{
  __shared__ __align__(16) f16 smem[10000 * 8];   // 160000 B arena
  int* s_addr = (int*)&smem[G_ADDR * 8];

  const int tid = threadIdx.x;
  const int wi = blockIdx.x >> 6, wj = blockIdx.x & 63;
  const int wv = tid >> 6;
  const int l = tid & 63;
  const int l15 = l & 15, lg = l >> 4;
  const f32x4 zero4 = {0.f, 0.f, 0.f, 0.f};
  const float QMULT = 0.17677669529663687f * 1.4426950408889634f; // scale*log2e

  // ---------------- Phase 0: scatter LUT + rolled x window (f16) ------------
  if (tid < 64) {
    int val = 0;
    if (tid < 49) {
      int i2 = tid / 7, j2 = tid - i2 * 7;
      int y = (wi & 15) * 7 + i2 + 3;  if (y >= 112) y -= 112;
      int xc = wj * 7 + j2 + 3;        if (xc >= 448) xc -= 448;
      val = (y * 448 + xc) * 768;
    }
    s_addr[tid] = val;
  }
  for (int gid = tid; gid < 1536; gid += 1024) {
    int t = gid / 24, g = gid - t * 24;
    f16x8 v;
    if (t < 49) {
      int hh = wi * 7 + t / 7 + 3; if (hh >= 448) hh -= 448;
      int ww = wj * 7 + t % 7 + 3; if (ww >= 448) ww -= 448;
      v = cvt8z(x + (size_t)(hh * 448 + ww) * 192 + g * 8);
    } else {
#pragma unroll
      for (int e = 0; e < 8; ++e) v[e] = (f16)0.0f;
    }
    *(f16x8*)&smem[(G_XIN + t * 25 + g) * 8] = v;
  }
  __syncthreads();

  // ---------------- Phase 1: QKV. waves 0-11: q/k (swapped); 12-15: v -------
  if (wv < 12) {
    // hoisted epilogue biases: latency hides under the GEMM below
    float4 b4a = *(const float4*)(bqkv + (2 * wv) * 16 + lg * 4);
    float4 b4b = *(const float4*)(bqkv + (2 * wv + 1) * 16 + lg * 4);
    f32x4 aqk[2][4];
#pragma unroll
    for (int ci = 0; ci < 2; ++ci)
#pragma unroll
      for (int t = 0; t < 4; ++t) aqk[ci][t] = zero4;

#pragma unroll
    for (int kc = 0; kc < 6; ++kc) {
      f16x8 xf[4];
#pragma unroll
      for (int t = 0; t < 4; ++t)
        xf[t] = *(const f16x8*)&smem[(G_XIN + (t * 16 + l15) * 25 + kc * 4 + lg) * 8];
      f16x8 wq0 = load_bq<USE_WS>(ws, Wqkv, kc, 2 * wv, l);
      f16x8 wq1 = load_bq<USE_WS>(ws, Wqkv, kc, 2 * wv + 1, l);
#pragma unroll
      for (int t = 0; t < 4; ++t) aqk[0][t] = MFMA16(wq0, xf[t], aqk[0][t]);
#pragma unroll
      for (int t = 0; t < 4; ++t) aqk[1][t] = MFMA16(wq1, xf[t], aqk[1][t]);
    }

#pragma unroll
    for (int ci = 0; ci < 2; ++ci) {
      int c0 = (2 * wv + ci) * 16 + lg * 4;       // 0..383
      float4 b4 = ci ? b4b : b4a;
      int part = (c0 >= 192) ? 1 : 0;
      int ch = c0 - part * 192;
      float mult = part ? 1.0f : QMULT;
      float bx = b4.x * mult, by = b4.y * mult, bz = b4.z * mult, bw = b4.w * mult;
      int gbase = (part ? G_K : G_Q) + (ch >> 3);
      int sub = ch & 7;
#pragma unroll
      for (int t = 0; t < 4; ++t) {
        int tok = t * 16 + l15;
        f16x4 v = pk4(fmaf(aqk[ci][t][0], mult, bx), fmaf(aqk[ci][t][1], mult, by),
                      fmaf(aqk[ci][t][2], mult, bz), fmaf(aqk[ci][t][3], mult, bw));
        *(f16x4*)&smem[(gbase + tok * 25) * 8 + sub] = v;
      }
    }
  } else {
    const int cv0 = (wv - 12) * 3;
    float bv0 = bqkv[384 + (cv0 + 0) * 16 + l15];
    float bv1 = bqkv[384 + (cv0 + 1) * 16 + l15];
    float bv2 = bqkv[384 + (cv0 + 2) * 16 + l15];
    f32x4 av[3][4];
#pragma unroll
    for (int ci = 0; ci < 3; ++ci)
#pragma unroll
      for (int t = 0; t < 4; ++t) av[ci][t] = zero4;

#pragma unroll
    for (int kc = 0; kc < 6; ++kc) {
      f16x8 xf[4];
#pragma unroll
      for (int t = 0; t < 4; ++t)
        xf[t] = *(const f16x8*)&smem[(G_XIN + (t * 16 + l15) * 25 + kc * 4 + lg) * 8];
      f16x8 w0 = load_bq<USE_WS>(ws, Wqkv, kc, 24 + cv0, l);
      f16x8 w1 = load_bq<USE_WS>(ws, Wqkv, kc, 24 + cv0 + 1, l);
      f16x8 w2 = load_bq<USE_WS>(ws, Wqkv, kc, 24 + cv0 + 2, l);
#pragma unroll
      for (int t = 0; t < 4; ++t) {
        av[0][t] = MFMA16(xf[t], w0, av[0][t]);
        av[1][t] = MFMA16(xf[t], w1, av[1][t]);
        av[2][t] = MFMA16(xf[t], w2, av[2][t]);
      }
    }

    const float bvv[3] = {bv0, bv1, bv2};
#pragma unroll
    for (int ci = 0; ci < 3; ++ci) {
      int vch = (cv0 + ci) * 16 + l15;            // 0..191
      float bv_ = bvv[ci];
#pragma unroll
      for (int t = 0; t < 4; ++t) {
        f16x4 v = pk4(av[ci][t][0] + bv_, av[ci][t][1] + bv_,
                      av[ci][t][2] + bv_, av[ci][t][3] + bv_);
        *(f16x4*)&smem[(G_VT + vch * 9 + 2 * t + (lg >> 1)) * 8 + (lg & 1) * 4] = v;
      }
    }
  }
  __syncthreads();

  // ---------------- Phase 2: attention ---------------------------------------
  {
    const int pt = wv & 3, hi = wv >> 2;
    const int p = 16 * pt + l15;
    const bool edge = (wi == 63) || (wj == 63);
    unsigned mbits = 0;
    int moff[16];
    if (edge || !USE_WS) {
      int pi = p / 7, pj = p - pi * 7;
#pragma unroll
      for (int jq = 0; jq < 4; ++jq)
#pragma unroll
        for (int r = 0; r < 4; ++r) {
          int q = 16 * jq + lg * 4 + r;
          int qi = q / 7, qj = q - qi * 7;
          bool bad = (q >= 49) || (p >= 49) ||
                     ((wi == 63) && ((pi < 4) != (qi < 4))) ||
                     ((wj == 63) && ((pj < 4) != (qj < 4)));
          int idx = jq * 4 + r;
          moff[idx] = bad ? 0 : (pi - qi + 6) * 13 + (pj - qj + 6);
          if (bad) mbits |= (1u << idx);
        }
    }

    if constexpr (USE_WS) {
      const f16* bb_base = ws + WS_BIAS_ELEM + p * 68 + lg * 4;
      if (hi < 2) attn_fast<2>(smem, bb_base, hi * 2, p, lg, l15, mbits, edge);
      else        attn_fast<1>(smem, bb_base, hi + 2, p, lg, l15, mbits, edge);
    } else {
      // fallback: sequential heads, per-lane global relpos gather
      const int h_first = (hi < 2) ? (hi * 2) : (hi + 2);
      const int h_count = (hi < 2) ? 2 : 1;
      float gaus[16];
#pragma unroll
      for (int jq = 0; jq < 4; ++jq)
#pragma unroll
        for (int r = 0; r < 4; ++r) {
          int q = 16 * jq + lg * 4 + r;
          int qi = q / 7, qj = q - qi * 7;
          int pi = p / 7, pj = p - pi * 7;
          int di = pi - qi, dj = pj - qj;
          gaus[jq * 4 + r] = __expf((float)(di * di + dj * dj) * (-9.0f / 98.0f));
        }
      for (int e = 0; e < h_count; ++e) {
        int h = h_first + e;
        f16x8 aq = *(const f16x8*)&smem[(G_Q + p * 25 + h * 4 + lg) * 8];
        f32x4 sc[4];
#pragma unroll
        for (int jq = 0; jq < 4; ++jq) {
          f16x8 bk = *(const f16x8*)&smem[(G_K + (16 * jq + l15) * 25 + h * 4 + lg) * 8];
          sc[jq] = MFMA16(bk, aq, zero4);
        }
        float sv[16];
        float sum = 0.0f;
#pragma unroll
        for (int jq = 0; jq < 4; ++jq)
#pragma unroll
          for (int r = 0; r < 4; ++r) {
            int idx = jq * 4 + r;
            float s = (mbits >> idx & 1u)
                ? -30000.0f
                : sc[jq][r] + (relpos[h * 169 + moff[idx]] + gaus[idx]) * 1.4426950408889634f;
            float ev = fast_exp2(s);
            sv[idx] = ev;
            sum += ev;
          }
#pragma unroll
        for (int jq = 0; jq < 4; ++jq) {
          f16x4 v = pk4(sv[jq * 4], sv[jq * 4 + 1], sv[jq * 4 + 2], sv[jq * 4 + 3]);
          *(f16x4*)&smem[(G_P + h * 576 + p * 9 + 2 * jq + (lg >> 1)) * 8 + (lg & 1) * 4] = v;
        }
        sum += __shfl_xor(sum, 16);
        sum += __shfl_xor(sum, 32);
        float inv = __builtin_amdgcn_rcpf(sum);
        f32x4 o[2] = {zero4, zero4};
#pragma unroll
        for (int kq = 0; kq < 2; ++kq) {
          f16x8 ap = *(const f16x8*)&smem[(G_P + h * 576 + p * 9 + kq * 4 + lg) * 8];
#pragma unroll
          for (int jn = 0; jn < 2; ++jn) {
            int ch = h * 32 + jn * 16 + l15;
            f16x8 bv = *(const f16x8*)&smem[(G_VT + ch * 9 + kq * 4 + lg) * 8];
            o[jn] = MFMA16(bv, ap, o[jn]);
          }
        }
#pragma unroll
        for (int jn = 0; jn < 2; ++jn) {
          int ch0 = h * 32 + jn * 16 + lg * 4;
          f16x4 v = pk4(o[jn][0] * inv, o[jn][1] * inv, o[jn][2] * inv, o[jn][3] * inv);
          *(f16x4*)&smem[(G_O + p * 25 + (ch0 >> 3)) * 8 + (ch0 & 7)] = v;
        }
      }
    }
  }
  __syncthreads();

  // ---------------- Phase 3: out-proj, wave = 1 ch-tile x 4 token-tiles -----
  // (Wout fragment loaded ONCE per block: 72 KB L2 traffic)
  if (wv < 12) {
    const int ct = wv;                    // ch-tile 0..11
    const float bias = bout[ct * 16 + l15];
    f32x4 acc[4];
#pragma unroll
    for (int t = 0; t < 4; ++t) acc[t] = zero4;

#pragma unroll
    for (int kc = 0; kc < 6; ++kc) {
      f16x8 b = load_bo<USE_WS>(ws, Wout, kc, ct, l);
      f16x8 a[4];
#pragma unroll
      for (int t = 0; t < 4; ++t)
        a[t] = *(const f16x8*)&smem[(G_O + (t * 16 + l15) * 25 + kc * 4 + lg) * 8];
#pragma unroll
      for (int t = 0; t < 4; ++t) acc[t] = MFMA16(a[t], b, acc[t]);
    }

    const int rr = wi >> 4;
    const int lane_off = rr * 192 + ct * 16 + l15;
#pragma unroll
    for (int t = 0; t < 4; ++t) {
#pragma unroll
      for (int r = 0; r < 4; ++r) {
        int pp = t * 16 + lg * 4 + r;
        if (pp < 49) {
          __builtin_nontemporal_store(acc[t][r] + bias, out + s_addr[pp] + lane_off);
        }
      }
    }
  }
}

extern "C" void kernel_launch(void* const* d_in, const int* in_sizes, int n_in,
                              void* d_out, int out_size, void* d_ws, size_t ws_size,
                              hipStream_t stream) {
  const float* x      = (const float*)d_in[0];
  const float* Wqkv   = (const float*)d_in[1];
  const float* bqkv   = (const float*)d_in[2];
  const float* relpos = (const float*)d_in[3];
  const float* Wout   = (const float*)d_in[4];
  const float* bout   = (const float*)d_in[5];
  float* out = (float*)d_out;
  f16* ws = (f16*)d_ws;

  if (ws_size >= (size_t)WS_NEED) {
    wmsa_prep<<<174, 256, 0, stream>>>(Wqkv, Wout, relpos, ws);
    wmsa_main<true><<<4096, 1024, 0, stream>>>(x, Wqkv, bqkv, relpos, Wout, bout, ws, out);
  } else {
    wmsa_main<false><<<4096, 1024, 0, stream>>>(x, Wqkv, bqkv, relpos, Wout, bout, ws, out);
  }
}